// Round 1
// baseline (158.356 us; speedup 1.0000x reference)
//
#include <hip/hip_runtime.h>
#include <hip/hip_bf16.h>

// Problem constants (B, L, H, HS, OUT) = (4, 512, 768, 64, 16)
#define Bc   4
#define Lc   512
#define Hc   768
#define HSc  64
#define OUTc 16
#define Pc   131328   // L*(L+1)/2

// Workspace layout (floats):
//   q   : B*L*HS = 131072   @ 0
//   k   : 131072            @ 131072
//   A   : B*L*OUT = 32768   @ 262144
//   E   : 32768             @ 294912
// total 327680 floats = 1.28 MB

// Kernel 1: fused q/k projection + per-token A/E projections.
// Grid: 256 blocks, 256 threads. Each block: 8 tokens.
// Thread layout phase A: n = tid&127 (output col: 0..63 -> q, 64..127 -> k),
// mg = tid>>7 selects token sub-group (wave-uniform -> scalar x loads).
__global__ __launch_bounds__(256) void qk_proj_kernel(
    const float* __restrict__ x,
    const float* __restrict__ Wq, const float* __restrict__ bq,
    const float* __restrict__ Wk, const float* __restrict__ bk,
    const float* __restrict__ Wb, const float* __restrict__ bb,
    float* __restrict__ qws, float* __restrict__ kws,
    float* __restrict__ Aws, float* __restrict__ Ews)
{
    __shared__ float lds_qk[8][128];   // [local token][q(0..63)|k(64..127)]

    const int tid = threadIdx.x;
    const int n   = tid & 127;
    const int mg  = __builtin_amdgcn_readfirstlane(tid >> 7);  // wave-uniform
    const int tok_base = blockIdx.x * 8 + mg * 4;

    const bool is_q = (n < 64);
    const float* Wp = is_q ? Wq : Wk;   // wave-uniform select
    const int col = n & 63;

    const float* xr = x + (size_t)tok_base * Hc;

    float acc0 = 0.f, acc1 = 0.f, acc2 = 0.f, acc3 = 0.f;
    #pragma unroll 4
    for (int j = 0; j < Hc; ++j) {
        float w  = Wp[j * HSc + col];     // coalesced 256B per wave
        float x0 = xr[j];                 // wave-uniform -> scalar load
        float x1 = xr[Hc + j];
        float x2 = xr[2 * Hc + j];
        float x3 = xr[3 * Hc + j];
        acc0 += x0 * w;
        acc1 += x1 * w;
        acc2 += x2 * w;
        acc3 += x3 * w;
    }
    const float bias = is_q ? bq[col] : bk[col];
    acc0 += bias; acc1 += bias; acc2 += bias; acc3 += bias;

    float* dst = is_q ? qws : kws;
    dst[(size_t)(tok_base + 0) * HSc + col] = acc0;
    dst[(size_t)(tok_base + 1) * HSc + col] = acc1;
    dst[(size_t)(tok_base + 2) * HSc + col] = acc2;
    dst[(size_t)(tok_base + 3) * HSc + col] = acc3;

    const int tl0 = mg * 4;
    lds_qk[tl0 + 0][n] = acc0;
    lds_qk[tl0 + 1][n] = acc1;
    lds_qk[tl0 + 2][n] = acc2;
    lds_qk[tl0 + 3][n] = acc3;

    __syncthreads();

    // Phase B: A[t] and E[t]. 8 tokens x 32 cols = 256 threads.
    const int tl = tid >> 5;        // local token 0..7
    const int c  = tid & 31;        // 0..15 -> A, 16..31 -> E
    const int tok = blockIdx.x * 8 + tl;
    const float* row = lds_qk[tl];

    if (c < 16) {
        float a = 0.f;
        #pragma unroll 8
        for (int h = 0; h < 64; ++h)
            a += row[h] * Wb[h * OUTc + c];
        Aws[(size_t)tok * OUTc + c] = a;
    } else {
        const int o = c - 16;
        float ev = bb[o];
        #pragma unroll 8
        for (int h = 0; h < 64; ++h) {
            ev += row[h]      * Wb[(128 + h) * OUTc + o];                         // q_end block
            ev += row[64 + h] * (Wb[(64 + h) * OUTc + o] + Wb[(192 + h) * OUTc + o]); // k_end blocks
        }
        Ews[(size_t)tok * OUTc + o] = ev;
    }
}

// Kernel 2: pair streaming. Grid (256, 4): blockIdx.x = j (s-pair {j, L-1-j},
// exactly 513 pairs per block -> perfect balance), blockIdx.y = b.
__global__ __launch_bounds__(256) void pair_kernel(
    const float* __restrict__ qws, const float* __restrict__ kws,
    const float* __restrict__ Aws, const float* __restrict__ Ews,
    float* __restrict__ out)
{
    __shared__ alignas(16) float lds_q[2][HSc];
    __shared__ alignas(16) float lds_A[2][OUTc];

    const int j = blockIdx.x;
    const int b = blockIdx.y;
    const int s1 = j;
    const int s2 = Lc - 1 - j;
    const int n1 = Lc - s1;          // run length for s1

    const int tid = threadIdx.x;
    if (tid < 64) {
        lds_q[0][tid] = qws[((size_t)b * Lc + s1) * HSc + tid];
    } else if (tid < 128) {
        lds_q[1][tid - 64] = qws[((size_t)b * Lc + s2) * HSc + (tid - 64)];
    } else if (tid < 144) {
        lds_A[0][tid - 128] = Aws[((size_t)b * Lc + s1) * OUTc + (tid - 128)];
    } else if (tid < 160) {
        lds_A[1][tid - 144] = Aws[((size_t)b * Lc + s2) * OUTc + (tid - 144)];
    }
    __syncthreads();

    // triangular row offsets: P_s = s*(2L+1-s)/2
    const int P1 = s1 * (2 * Lc + 1 - s1) / 2;
    const int P2 = s2 * (2 * Lc + 1 - s2) / 2;

    for (int t = tid; t < Lc + 1; t += 256) {
        const int which = (t < n1) ? 0 : 1;
        const int e   = which ? (s2 + (t - n1)) : (s1 + t);
        const int row = which ? (P2 + (e - s2)) : (P1 + (e - s1));

        const float4* kk = (const float4*)(kws + ((size_t)b * Lc + e) * HSc);
        const float4* qq = (const float4*)lds_q[which];

        float sc = 0.f;
        #pragma unroll
        for (int i = 0; i < 16; ++i) {
            float4 kv = kk[i];
            float4 qv = qq[i];
            sc += qv.x * kv.x + qv.y * kv.y + qv.z * kv.z + qv.w * kv.w;
        }

        const float4* Ee = (const float4*)(Ews + ((size_t)b * Lc + e) * OUTc);
        const float4* Aa = (const float4*)lds_A[which];
        float4* op = (float4*)(out + ((size_t)b * Pc + row) * OUTc);
        #pragma unroll
        for (int i = 0; i < 4; ++i) {
            float4 ev = Ee[i];
            float4 av = Aa[i];
            float4 r;
            r.x = av.x + ev.x + sc;
            r.y = av.y + ev.y + sc;
            r.z = av.z + ev.z + sc;
            r.w = av.w + ev.w + sc;
            op[i] = r;
        }
    }
}

extern "C" void kernel_launch(void* const* d_in, const int* in_sizes, int n_in,
                              void* d_out, int out_size, void* d_ws, size_t ws_size,
                              hipStream_t stream) {
    const float* x  = (const float*)d_in[0];
    const float* Wq = (const float*)d_in[1];
    const float* bq = (const float*)d_in[2];
    const float* Wk = (const float*)d_in[3];
    const float* bk = (const float*)d_in[4];
    const float* Wb = (const float*)d_in[5];
    const float* bb = (const float*)d_in[6];

    float* ws  = (float*)d_ws;
    float* qws = ws;
    float* kws = ws + 131072;
    float* Aws = ws + 262144;
    float* Ews = ws + 294912;

    qk_proj_kernel<<<dim3(256), dim3(256), 0, stream>>>(
        x, Wq, bq, Wk, bk, Wb, bb, qws, kws, Aws, Ews);
    pair_kernel<<<dim3(256, 4), dim3(256), 0, stream>>>(
        qws, kws, Aws, Ews, (float*)d_out);
}

// Round 2
// 108.530 us; speedup vs baseline: 1.4591x; 1.4591x over previous
//
#include <hip/hip_runtime.h>
#include <hip/hip_bf16.h>

// Problem constants (B, L, H, HS, OUT) = (4, 512, 768, 64, 16)
#define Bc   4
#define Lc   512
#define Hc   768
#define HSc  64
#define OUTc 16
#define Pc   131328   // L*(L+1)/2
#define KH   384      // K-half for in-block K-split

// Workspace layout (floats):
//   q   : B*L*HS = 131072   @ 0
//   k   : 131072            @ 131072
//   A   : B*L*OUT = 32768   @ 262144
//   E   : 32768             @ 294912

// Kernel 1: fused q/k projection + per-token A/E projections.
// Grid: 512 blocks x 256 threads; block = 4 tokens.
// Waves: w0 = q-cols K-half0, w1 = k-cols KH0, w2 = q KH1, w3 = k KH1.
// Each thread: 4 token accumulators over its K-half; partials combined in LDS.
// W loads coalesced (256B/wave/iter), x loads wave-uniform -> scalar s_load.
__global__ __launch_bounds__(256) void qk_proj_kernel(
    const float* __restrict__ x,
    const float* __restrict__ Wq, const float* __restrict__ bq,
    const float* __restrict__ Wk, const float* __restrict__ bk,
    const float* __restrict__ Wb, const float* __restrict__ bb,
    float* __restrict__ qws, float* __restrict__ kws,
    float* __restrict__ Aws, float* __restrict__ Ews)
{
    __shared__ float lds_p[2][4][128];   // [K-half][local token][q(0..63)|k(64..127)]
    __shared__ float lds_c[4][128];      // combined q|k per token

    const int tid = threadIdx.x;
    const int n   = tid & 127;                                   // col slot (q:0-63, k:64-127)
    const int wu  = __builtin_amdgcn_readfirstlane(tid >> 6);    // wave id 0..3 (uniform)
    const int kh  = wu >> 1;                                     // K-half 0/1
    const bool is_q = ((wu & 1) == 0);
    const int col = n & 63;
    const int tok_base = blockIdx.x * 4;

    const float* Wp = is_q ? Wq : Wk;                            // wave-uniform select
    const float* wp = Wp + (size_t)kh * KH * HSc + col;          // per-lane column base
    const float* xr = x + (size_t)tok_base * Hc + kh * KH;       // wave-uniform -> s_load

    float acc0 = 0.f, acc1 = 0.f, acc2 = 0.f, acc3 = 0.f;
    for (int j0 = 0; j0 < KH; j0 += 16) {
        float w[16];
        #pragma unroll
        for (int u = 0; u < 16; ++u)
            w[u] = wp[(j0 + u) * HSc];          // 16 independent 256B coalesced loads
        #pragma unroll
        for (int u = 0; u < 16; ++u) {
            const int jj = j0 + u;
            const float x0 = xr[jj];
            const float x1 = xr[Hc + jj];
            const float x2 = xr[2 * Hc + jj];
            const float x3 = xr[3 * Hc + jj];
            acc0 += x0 * w[u];
            acc1 += x1 * w[u];
            acc2 += x2 * w[u];
            acc3 += x3 * w[u];
        }
    }

    lds_p[kh][0][n] = acc0;
    lds_p[kh][1][n] = acc1;
    lds_p[kh][2][n] = acc2;
    lds_p[kh][3][n] = acc3;
    __syncthreads();

    // Combine K-halves + bias, store q/k, keep combined copy in LDS for phase B.
    for (int i = tid; i < 512; i += 256) {
        const int t = i >> 7;
        const int c = i & 127;
        float v = lds_p[0][t][c] + lds_p[1][t][c];
        const int cc = c & 63;
        if (c < 64) { v += bq[cc]; qws[(size_t)(tok_base + t) * HSc + cc] = v; }
        else        { v += bk[cc]; kws[(size_t)(tok_base + t) * HSc + cc] = v; }
        lds_c[t][c] = v;
    }
    __syncthreads();

    // Phase B: A[t] = q@Wb[0:64]; E[t] = q@Wb[128:192] + k@(Wb[64:128]+Wb[192:256]) + bb.
    // 4 tokens x 32 cols = 128 active threads.
    if (tid < 128) {
        const int t = tid >> 5;
        const int c = tid & 31;
        const int tok = tok_base + t;
        const float* row = lds_c[t];
        if (c < 16) {
            float a = 0.f;
            #pragma unroll 8
            for (int h = 0; h < 64; ++h)
                a += row[h] * Wb[h * OUTc + c];
            Aws[(size_t)tok * OUTc + c] = a;
        } else {
            const int o = c - 16;
            float ev = bb[o];
            #pragma unroll 8
            for (int h = 0; h < 64; ++h) {
                ev += row[h]      * Wb[(128 + h) * OUTc + o];
                ev += row[64 + h] * (Wb[(64 + h) * OUTc + o] + Wb[(192 + h) * OUTc + o]);
            }
            Ews[(size_t)tok * OUTc + o] = ev;
        }
    }
}

// Kernel 2: pair streaming, 4 lanes per pair for coalescing.
// Grid (256, 4): blockIdx.x = j -> s-pair {j, 511-j} (513 pairs, balanced),
// blockIdx.y = b. 256 threads = 64 pair-slots x 4 lanes.
// Lane l of a pair handles float4 chunks {l, l+4, l+8, l+12} of the 64-float k/q
// rows (64B-contiguous per 4-lane group) and writes output floats [4l,4l+4).
__global__ __launch_bounds__(256) void pair_kernel(
    const float* __restrict__ qws, const float* __restrict__ kws,
    const float* __restrict__ Aws, const float* __restrict__ Ews,
    float* __restrict__ out)
{
    __shared__ alignas(16) float lds_q[2][HSc];
    __shared__ alignas(16) float lds_A[2][OUTc];

    const int j = blockIdx.x;
    const int b = blockIdx.y;
    const int s1 = j;
    const int s2 = Lc - 1 - j;
    const int n1 = Lc - s1;          // pairs in s1's run

    const int tid = threadIdx.x;
    if (tid < 64) {
        lds_q[0][tid] = qws[((size_t)b * Lc + s1) * HSc + tid];
    } else if (tid < 128) {
        lds_q[1][tid - 64] = qws[((size_t)b * Lc + s2) * HSc + (tid - 64)];
    } else if (tid < 144) {
        lds_A[0][tid - 128] = Aws[((size_t)b * Lc + s1) * OUTc + (tid - 128)];
    } else if (tid < 160) {
        lds_A[1][tid - 144] = Aws[((size_t)b * Lc + s2) * OUTc + (tid - 144)];
    }
    __syncthreads();

    const int P1 = s1 * (2 * Lc + 1 - s1) / 2;
    const int P2 = s2 * (2 * Lc + 1 - s2) / 2;
    const int lane = tid & 3;

    const float* kb = kws + (size_t)b * Lc * HSc;
    const float* Eb = Ews + (size_t)b * Lc * OUTc;
    float* ob = out + (size_t)b * Pc * OUTc;

    for (int p = tid >> 2; p < Lc + 1; p += 64) {
        const int which = (p < n1) ? 0 : 1;
        const int e   = which ? (s2 + (p - n1)) : (s1 + p);
        const int row = which ? (P2 + (p - n1)) : (P1 + p);

        const float4* kk = (const float4*)(kb + (size_t)e * HSc);
        const float4* qq = (const float4*)lds_q[which];

        float sc = 0.f;
        #pragma unroll
        for (int i = 0; i < 4; ++i) {
            float4 kv = kk[i * 4 + lane];
            float4 qv = qq[i * 4 + lane];
            sc += qv.x * kv.x + qv.y * kv.y + qv.z * kv.z + qv.w * kv.w;
        }
        sc += __shfl_xor(sc, 1);
        sc += __shfl_xor(sc, 2);

        const float4 ev = ((const float4*)(Eb + (size_t)e * OUTc))[lane];
        const float4 av = ((const float4*)lds_A[which])[lane];
        float4 r;
        r.x = av.x + ev.x + sc;
        r.y = av.y + ev.y + sc;
        r.z = av.z + ev.z + sc;
        r.w = av.w + ev.w + sc;
        ((float4*)(ob + (size_t)row * OUTc))[lane] = r;
    }
}

extern "C" void kernel_launch(void* const* d_in, const int* in_sizes, int n_in,
                              void* d_out, int out_size, void* d_ws, size_t ws_size,
                              hipStream_t stream) {
    const float* x  = (const float*)d_in[0];
    const float* Wq = (const float*)d_in[1];
    const float* bq = (const float*)d_in[2];
    const float* Wk = (const float*)d_in[3];
    const float* bk = (const float*)d_in[4];
    const float* Wb = (const float*)d_in[5];
    const float* bb = (const float*)d_in[6];

    float* ws  = (float*)d_ws;
    float* qws = ws;
    float* kws = ws + 131072;
    float* Aws = ws + 262144;
    float* Ews = ws + 294912;

    qk_proj_kernel<<<dim3(512), dim3(256), 0, stream>>>(
        x, Wq, bq, Wk, bk, Wb, bb, qws, kws, Aws, Ews);
    pair_kernel<<<dim3(256, 4), dim3(256), 0, stream>>>(
        qws, kws, Aws, Ews, (float*)d_out);
}

// Round 4
// 100.221 us; speedup vs baseline: 1.5801x; 1.0829x over previous
//
#include <hip/hip_runtime.h>
#include <hip/hip_bf16.h>

// Problem constants (B, L, H, HS, OUT) = (4, 512, 768, 64, 16)
#define Bc   4
#define Lc   512
#define Hc   768
#define HSc  64
#define OUTc 16
#define Pc   131328   // L*(L+1)/2
#define KSEG 192      // K quarter (768/4)

typedef float floatx4 __attribute__((ext_vector_type(4)));  // native vec for nontemporal builtin

// Workspace layout (floats): q@0, k@131072, A@262144, E@294912

// Kernel 1: fused q/k projection + per-token A/E projections.
// Grid: 512 blocks x 512 threads (8 waves); block = 4 tokens.
// Wave wu: half = wu&1 (q or k cols), kseg = wu>>1 (K range [kseg*192,+192)).
// Double-buffered 16-deep W prefetch; x loads wave-uniform -> scalar s_load.
__global__ __launch_bounds__(512, 4) void qk_proj_kernel(
    const float* __restrict__ x,
    const float* __restrict__ Wq, const float* __restrict__ bq,
    const float* __restrict__ Wk, const float* __restrict__ bk,
    const float* __restrict__ Wb, const float* __restrict__ bb,
    float* __restrict__ qws, float* __restrict__ kws,
    float* __restrict__ Aws, float* __restrict__ Ews)
{
    __shared__ float lds_p[4][4][128];   // [kseg][local token][q(0..63)|k(64..127)]
    __shared__ float lds_c[4][128];      // combined q|k per token

    const int tid = threadIdx.x;
    const int wu  = __builtin_amdgcn_readfirstlane(tid >> 6);  // wave id 0..7
    const int half = wu & 1;                                   // 0=q, 1=k
    const int kseg = wu >> 1;                                  // 0..3
    const int col  = tid & 63;
    const int tok_base = blockIdx.x * 4;

    const float* Wp = half ? Wk : Wq;                          // wave-uniform
    const float* wp = Wp + (size_t)kseg * KSEG * HSc + col;
    const float* xr = x + (size_t)tok_base * Hc + kseg * KSEG; // uniform -> s_load

    float acc0 = 0.f, acc1 = 0.f, acc2 = 0.f, acc3 = 0.f;
    float wA[16], wB[16];

    #pragma unroll
    for (int u = 0; u < 16; ++u) wA[u] = wp[u * HSc];

    #pragma unroll 1
    for (int j0 = 0; j0 < KSEG; j0 += 32) {
        // prefetch next-16 into wB while computing wA
        #pragma unroll
        for (int u = 0; u < 16; ++u) wB[u] = wp[(j0 + 16 + u) * HSc];
        #pragma unroll
        for (int u = 0; u < 16; ++u) {
            const int jj = j0 + u;
            const float x0 = xr[jj];
            const float x1 = xr[Hc + jj];
            const float x2 = xr[2 * Hc + jj];
            const float x3 = xr[3 * Hc + jj];
            acc0 += x0 * wA[u];
            acc1 += x1 * wA[u];
            acc2 += x2 * wA[u];
            acc3 += x3 * wA[u];
        }
        // prefetch following-16 into wA while computing wB
        if (j0 + 32 < KSEG) {
            #pragma unroll
            for (int u = 0; u < 16; ++u) wA[u] = wp[(j0 + 32 + u) * HSc];
        }
        #pragma unroll
        for (int u = 0; u < 16; ++u) {
            const int jj = j0 + 16 + u;
            const float x0 = xr[jj];
            const float x1 = xr[Hc + jj];
            const float x2 = xr[2 * Hc + jj];
            const float x3 = xr[3 * Hc + jj];
            acc0 += x0 * wB[u];
            acc1 += x1 * wB[u];
            acc2 += x2 * wB[u];
            acc3 += x3 * wB[u];
        }
    }

    const int n = half * 64 + col;
    lds_p[kseg][0][n] = acc0;
    lds_p[kseg][1][n] = acc1;
    lds_p[kseg][2][n] = acc2;
    lds_p[kseg][3][n] = acc3;
    __syncthreads();

    // Combine 4 K-segments + bias; store q/k; keep combined copy for phase B.
    if (tid < 512) {
        const int t = tid >> 7;
        const int c = tid & 127;
        float v = lds_p[0][t][c] + lds_p[1][t][c] + lds_p[2][t][c] + lds_p[3][t][c];
        const int cc = c & 63;
        if (c < 64) { v += bq[cc]; qws[(size_t)(tok_base + t) * HSc + cc] = v; }
        else        { v += bk[cc]; kws[(size_t)(tok_base + t) * HSc + cc] = v; }
        lds_c[t][c] = v;
    }
    __syncthreads();

    // Phase B: A[t] = q@Wb[0:64]; E[t] = q@Wb[128:192] + k@(Wb[64:128]+Wb[192:256]) + bb
    if (tid < 128) {
        const int t = tid >> 5;
        const int c = tid & 31;
        const int tok = tok_base + t;
        const float* row = lds_c[t];
        if (c < 16) {
            float a = 0.f;
            #pragma unroll 8
            for (int h = 0; h < 64; ++h)
                a += row[h] * Wb[h * OUTc + c];
            Aws[(size_t)tok * OUTc + c] = a;
        } else {
            const int o = c - 16;
            float ev = bb[o];
            #pragma unroll 8
            for (int h = 0; h < 64; ++h) {
                ev += row[h]      * Wb[(128 + h) * OUTc + o];
                ev += row[64 + h] * (Wb[(64 + h) * OUTc + o] + Wb[(192 + h) * OUTc + o]);
            }
            Ews[(size_t)tok * OUTc + o] = ev;
        }
    }
}

// Kernel 2: pair streaming, 4 lanes per pair, 2 pairs in flight per step.
// Grid (256, 4): blockIdx.x = j -> s-pair {j, 511-j} (513 pairs), blockIdx.y = b.
__global__ __launch_bounds__(256) void pair_kernel(
    const float* __restrict__ qws, const float* __restrict__ kws,
    const float* __restrict__ Aws, const float* __restrict__ Ews,
    float* __restrict__ out)
{
    __shared__ alignas(16) float lds_q[2][HSc];
    __shared__ alignas(16) float lds_A[2][OUTc];

    const int j = blockIdx.x;
    const int b = blockIdx.y;
    const int s1 = j;
    const int s2 = Lc - 1 - j;
    const int n1 = Lc - s1;          // pairs in s1's run

    const int tid = threadIdx.x;
    if (tid < 64) {
        lds_q[0][tid] = qws[((size_t)b * Lc + s1) * HSc + tid];
    } else if (tid < 128) {
        lds_q[1][tid - 64] = qws[((size_t)b * Lc + s2) * HSc + (tid - 64)];
    } else if (tid < 144) {
        lds_A[0][tid - 128] = Aws[((size_t)b * Lc + s1) * OUTc + (tid - 128)];
    } else if (tid < 160) {
        lds_A[1][tid - 144] = Ews[0] * 0.f + Aws[((size_t)b * Lc + s2) * OUTc + (tid - 144)];
    }
    __syncthreads();

    const int P1 = s1 * (2 * Lc + 1 - s1) / 2;
    const int P2 = s2 * (2 * Lc + 1 - s2) / 2;
    const int lane = tid & 3;
    const int slot = tid >> 2;       // 0..63

    const float* kb = kws + (size_t)b * Lc * HSc;
    const float* Eb = Ews + (size_t)b * Lc * OUTc;
    float* ob = out + (size_t)b * Pc * OUTc;

    auto do_pair = [&](int p) {
        const int which = (p < n1) ? 0 : 1;
        const int e   = which ? (s2 + (p - n1)) : (s1 + p);
        const int row = which ? (P2 + (p - n1)) : (P1 + p);

        const float4* kk = (const float4*)(kb + (size_t)e * HSc);
        const float4* qq = (const float4*)lds_q[which];

        float4 kv0 = kk[lane];
        float4 kv1 = kk[4 + lane];
        float4 kv2 = kk[8 + lane];
        float4 kv3 = kk[12 + lane];
        const float4 ev = ((const float4*)(Eb + (size_t)e * OUTc))[lane];

        float4 qv0 = qq[lane];
        float4 qv1 = qq[4 + lane];
        float4 qv2 = qq[8 + lane];
        float4 qv3 = qq[12 + lane];

        float sc = qv0.x * kv0.x + qv0.y * kv0.y + qv0.z * kv0.z + qv0.w * kv0.w;
        sc += qv1.x * kv1.x + qv1.y * kv1.y + qv1.z * kv1.z + qv1.w * kv1.w;
        sc += qv2.x * kv2.x + qv2.y * kv2.y + qv2.z * kv2.z + qv2.w * kv2.w;
        sc += qv3.x * kv3.x + qv3.y * kv3.y + qv3.z * kv3.z + qv3.w * kv3.w;
        sc += __shfl_xor(sc, 1);
        sc += __shfl_xor(sc, 2);

        const float4 av = ((const float4*)lds_A[which])[lane];
        floatx4 r;
        r.x = av.x + ev.x + sc;
        r.y = av.y + ev.y + sc;
        r.z = av.z + ev.z + sc;
        r.w = av.w + ev.w + sc;
        __builtin_nontemporal_store(r, (floatx4*)(ob + (size_t)row * OUTc) + lane);
    };

    // pairs 0..511 in 4 double-steps (both loads in flight per step), pair 512 tail
    #pragma unroll
    for (int i = 0; i < 4; ++i) {
        do_pair(slot + 128 * i);
        do_pair(slot + 128 * i + 64);
    }
    if (slot == 0) do_pair(512);
}

extern "C" void kernel_launch(void* const* d_in, const int* in_sizes, int n_in,
                              void* d_out, int out_size, void* d_ws, size_t ws_size,
                              hipStream_t stream) {
    const float* x  = (const float*)d_in[0];
    const float* Wq = (const float*)d_in[1];
    const float* bq = (const float*)d_in[2];
    const float* Wk = (const float*)d_in[3];
    const float* bk = (const float*)d_in[4];
    const float* Wb = (const float*)d_in[5];
    const float* bb = (const float*)d_in[6];

    float* ws  = (float*)d_ws;
    float* qws = ws;
    float* kws = ws + 131072;
    float* Aws = ws + 262144;
    float* Ews = ws + 294912;

    qk_proj_kernel<<<dim3(512), dim3(512), 0, stream>>>(
        x, Wq, bq, Wk, bk, Wb, bb, qws, kws, Aws, Ews);
    pair_kernel<<<dim3(256, 4), dim3(256), 0, stream>>>(
        qws, kws, Aws, Ews, (float*)d_out);
}